// Round 9
// baseline (413.482 us; speedup 1.0000x reference)
//
#include <hip/hip_runtime.h>
#include <hip/hip_cooperative_groups.h>
#include <hip/hip_bf16.h>

namespace cg = cooperative_groups;

#define NN    4096
#define FIN   512
#define NH1   128
#define NH    4
#define NH2   256
#define NH3   64
#define CAP   64
#define ALPHA 0.2f
#define NBLK  512

typedef float f32x4 __attribute__((ext_vector_type(4)));
typedef __bf16 bf16x8 __attribute__((ext_vector_type(8)));

__device__ __forceinline__ unsigned short f2bf(float f) {
    union { float f; unsigned u; } x; x.f = f;
    unsigned r = x.u + 0x7fff + ((x.u >> 16) & 1);
    return (unsigned short)(r >> 16);
}
__device__ __forceinline__ float bf2f(ushort u) {
    union { unsigned u; float f; } x; x.u = ((unsigned)u) << 16;
    return x.f;
}
__device__ __forceinline__ float bflo(unsigned w) {
    union { unsigned u; float f; } x; x.u = w << 16; return x.f;
}
__device__ __forceinline__ float bfhi(unsigned w) {
    union { unsigned u; float f; } x; x.u = w & 0xffff0000u; return x.f;
}

// virtual-block ranges for phase 0
#define A_CSR   4096
#define A_X     (A_CSR + 2048)
#define A_WATT  (A_X + 1024)
#define A_W1T   (A_WATT + 512)
#define A_W2B   (A_W1T + 16)
#define A_Z     (A_W2B + 32)

struct MegaP {
    const float *adj, *x, *W_att, *a, *W1, *W2;
    ushort *xb, *Wattb, *W1t, *W2b, *Whb, *xrb, *y1b;
    float *s1, *s2, *y2, *out;
    int *nbr, *cnt;
};

// ---------------------------------------------------------------------------
// single-buffer MFMA GEMM tile (64x64, 4 waves), optional score epilogue
// ---------------------------------------------------------------------------
__device__ __forceinline__ void gemm_tile(const ushort* __restrict__ A,
                                          const ushort* __restrict__ Bt,
                                          ushort* __restrict__ Cb,
                                          const float* __restrict__ av,
                                          float* __restrict__ s1,
                                          float* __restrict__ s2,
                                          int N, int K, int bx, int by,
                                          bool scores, char* smem, int tid) {
    ushort* As = (ushort*)smem;
    ushort* Bs = (ushort*)(smem + 8192);
    const int wid = tid >> 6, lane = tid & 63;
    const int row0 = by * 64, col0 = bx * 64;
    const int wr = wid >> 1, wc = wid & 1;
    f32x4 acc[2][2] = {};

    for (int k0 = 0; k0 < K; k0 += 64) {
        __syncthreads();               // prior reads done before overwrite
        #pragma unroll
        for (int j = 0; j < 2; ++j) {
            int ci = j * 256 + tid;
            int r = ci >> 3;
            int sc = (ci & 7) ^ (r & 7);
            const ushort* ga = A + (size_t)(row0 + r) * K + k0 + sc * 8;
            const ushort* gb = Bt + (size_t)(col0 + r) * K + k0 + sc * 8;
            ushort* la = As + (j * 256 + wid * 64) * 8;
            ushort* lb = Bs + (j * 256 + wid * 64) * 8;
            __builtin_amdgcn_global_load_lds(
                (const __attribute__((address_space(1))) unsigned int*)ga,
                (__attribute__((address_space(3))) unsigned int*)la, 16, 0, 0);
            __builtin_amdgcn_global_load_lds(
                (const __attribute__((address_space(1))) unsigned int*)gb,
                (__attribute__((address_space(3))) unsigned int*)lb, 16, 0, 0);
        }
        __syncthreads();
        #pragma unroll
        for (int kk = 0; kk < 2; ++kk) {
            bf16x8 af[2], bfv[2];
            #pragma unroll
            for (int m = 0; m < 2; ++m) {
                int r = wr * 32 + m * 16 + (lane & 15);
                int kc = kk * 4 + (lane >> 4);
                int off = r * 64 + (((kc ^ (r & 7)) & 7) << 3);
                af[m] = *reinterpret_cast<const bf16x8*>(&As[off]);
            }
            #pragma unroll
            for (int n = 0; n < 2; ++n) {
                int c = wc * 32 + n * 16 + (lane & 15);
                int kc = kk * 4 + (lane >> 4);
                int off = c * 64 + (((kc ^ (c & 7)) & 7) << 3);
                bfv[n] = *reinterpret_cast<const bf16x8*>(&Bs[off]);
            }
            #pragma unroll
            for (int m = 0; m < 2; ++m)
                #pragma unroll
                for (int n = 0; n < 2; ++n)
                    acc[m][n] = __builtin_amdgcn_mfma_f32_16x16x32_bf16(af[m], bfv[n], acc[m][n], 0, 0, 0);
        }
    }
    #pragma unroll
    for (int m = 0; m < 2; ++m)
        #pragma unroll
        for (int n = 0; n < 2; ++n) {
            int col = col0 + wc * 32 + n * 16 + (lane & 15);
            #pragma unroll
            for (int j2 = 0; j2 < 4; ++j2) {
                int row = row0 + wr * 32 + m * 16 + (lane >> 4) * 4 + j2;
                Cb[(size_t)row * N + col] = f2bf(acc[m][n][j2]);
            }
        }
    if (scores) {
        int h = col0 >> 7;
        float a1v[2], a2v[2];
        #pragma unroll
        for (int n = 0; n < 2; ++n) {
            int colh = (col0 & 127) + wc * 32 + n * 16 + (lane & 15);
            a1v[n] = av[h * 256 + colh];
            a2v[n] = av[h * 256 + 128 + colh];
        }
        #pragma unroll
        for (int m = 0; m < 2; ++m)
            #pragma unroll
            for (int j2 = 0; j2 < 4; ++j2) {
                float v1 = acc[m][0][j2] * a1v[0] + acc[m][1][j2] * a1v[1];
                float v2 = acc[m][0][j2] * a2v[0] + acc[m][1][j2] * a2v[1];
                #pragma unroll
                for (int off = 1; off < 16; off <<= 1) {
                    v1 += __shfl_xor(v1, off);
                    v2 += __shfl_xor(v2, off);
                }
                if ((lane & 15) == 0) {
                    int row = row0 + wr * 32 + m * 16 + (lane >> 4) * 4 + j2;
                    atomicAdd(&s1[h * NN + row], v1);
                    atomicAdd(&s2[h * NN + row], v2);
                }
            }
    }
}

// ---------------------------------------------------------------------------
__device__ __forceinline__ void attn_node(const ushort* __restrict__ Whb,
                                          const float* __restrict__ s1,
                                          const float* __restrict__ s2,
                                          const int* __restrict__ nbr,
                                          const int* __restrict__ cnt,
                                          ushort* __restrict__ xrb,
                                          int n, int h, int lane) {
    int c = cnt[n];
    const int* nb = nbr + n * CAP;
    int m = (lane < c) ? nb[lane] : 0;
    float e = -1e30f;
    float s1n = s1[h * NN + n];
    if (lane < c) {
        float t = s1n + s2[h * NN + m];
        e = (t >= 0.0f) ? t : ALPHA * t;
    }
    float mx = e;
    #pragma unroll
    for (int off = 32; off; off >>= 1) mx = fmaxf(mx, __shfl_xor(mx, off));
    float p = (lane < c) ? __expf(e - mx) : 0.0f;
    float s = p;
    #pragma unroll
    for (int off = 32; off; off >>= 1) s += __shfl_xor(s, off);
    p /= s;
    const ushort* wb = Whb + h * 128 + 2 * lane;
    float acc0 = 0.0f, acc1 = 0.0f;
    int cp4 = (c + 3) & ~3;
    for (int j = 0; j < cp4; j += 4) {
        float p0 = __shfl(p, j),     p1 = __shfl(p, j + 1);
        float p2 = __shfl(p, j + 2), p3 = __shfl(p, j + 3);
        int   m0 = __shfl(m, j),     m1 = __shfl(m, j + 1);
        int   m2 = __shfl(m, j + 2), m3 = __shfl(m, j + 3);
        unsigned w0 = *reinterpret_cast<const unsigned*>(wb + (size_t)m0 * 512);
        unsigned w1 = *reinterpret_cast<const unsigned*>(wb + (size_t)m1 * 512);
        unsigned w2 = *reinterpret_cast<const unsigned*>(wb + (size_t)m2 * 512);
        unsigned w3 = *reinterpret_cast<const unsigned*>(wb + (size_t)m3 * 512);
        acc0 = fmaf(p0, bflo(w0), acc0); acc1 = fmaf(p0, bfhi(w0), acc1);
        acc0 = fmaf(p1, bflo(w1), acc0); acc1 = fmaf(p1, bfhi(w1), acc1);
        acc0 = fmaf(p2, bflo(w2), acc0); acc1 = fmaf(p2, bfhi(w2), acc1);
        acc0 = fmaf(p3, bflo(w3), acc0); acc1 = fmaf(p3, bfhi(w3), acc1);
    }
    unsigned ow = (unsigned)f2bf(fmaxf(acc0, 0.0f)) | ((unsigned)f2bf(fmaxf(acc1, 0.0f)) << 16);
    *reinterpret_cast<unsigned*>(xrb + (size_t)n * 512 + h * 128 + 2 * lane) = ow;
}

// ---------------------------------------------------------------------------
__device__ __forceinline__ void g1y2_node(const ushort* __restrict__ y1b,
                                          const int* __restrict__ nbr,
                                          const int* __restrict__ cnt,
                                          const ushort* __restrict__ W2b,
                                          float* __restrict__ y2,
                                          int n, int tid, char* smem) {
    float* g1s  = (float*)smem;            // 256 floats
    float* part = (float*)(smem + 1024);   // 4x64 floats
    int c = cnt[n];
    const int* nb = nbr + n * CAP;
    if (tid < 128) {
        float acc0 = 0.0f, acc1 = 0.0f;
        const ushort* yb = y1b + 2 * tid;
        for (int j = 0; j < c; j += 4) {
            int i0 = nb[j];
            int i1 = nb[(j + 1 < c) ? j + 1 : j];
            int i2 = nb[(j + 2 < c) ? j + 2 : j];
            int i3 = nb[(j + 3 < c) ? j + 3 : j];
            float f1 = (j + 1 < c) ? 1.f : 0.f;
            float f2 = (j + 2 < c) ? 1.f : 0.f;
            float f3 = (j + 3 < c) ? 1.f : 0.f;
            unsigned w0 = *reinterpret_cast<const unsigned*>(yb + (size_t)i0 * NH2);
            unsigned w1 = *reinterpret_cast<const unsigned*>(yb + (size_t)i1 * NH2);
            unsigned w2 = *reinterpret_cast<const unsigned*>(yb + (size_t)i2 * NH2);
            unsigned w3 = *reinterpret_cast<const unsigned*>(yb + (size_t)i3 * NH2);
            acc0 += bflo(w0); acc1 += bfhi(w0);
            acc0 = fmaf(f1, bflo(w1), acc0); acc1 = fmaf(f1, bfhi(w1), acc1);
            acc0 = fmaf(f2, bflo(w2), acc0); acc1 = fmaf(f2, bfhi(w2), acc1);
            acc0 = fmaf(f3, bflo(w3), acc0); acc1 = fmaf(f3, bfhi(w3), acc1);
        }
        g1s[2 * tid]     = fmaxf(acc0, 0.0f);
        g1s[2 * tid + 1] = fmaxf(acc1, 0.0f);
    }
    __syncthreads();
    int q = tid >> 6, col = tid & 63;
    float acc = 0.0f;
    #pragma unroll 8
    for (int i = 0; i < 64; ++i) {
        int k = q * 64 + i;
        acc = fmaf(g1s[k], bf2f(W2b[k * NH3 + col]), acc);
    }
    part[q * 64 + col] = acc;
    __syncthreads();
    if (tid < 64)
        y2[(size_t)n * NH3 + tid] = part[tid] + part[64 + tid] + part[128 + tid] + part[192 + tid];
}

// ---------------------------------------------------------------------------
__device__ __forceinline__ void final_node(const float* __restrict__ Y2,
                                           const int* __restrict__ nbr,
                                           const int* __restrict__ cnt,
                                           float* __restrict__ out,
                                           int n, int lane) {
    int c = cnt[n];
    const int* nb = nbr + n * CAP;
    float acc = 0.0f;
    for (int j = 0; j < c; j += 4) {
        int i0 = nb[j];
        int i1 = nb[(j + 1 < c) ? j + 1 : j];
        int i2 = nb[(j + 2 < c) ? j + 2 : j];
        int i3 = nb[(j + 3 < c) ? j + 3 : j];
        float f1 = (j + 1 < c) ? 1.f : 0.f;
        float f2 = (j + 2 < c) ? 1.f : 0.f;
        float f3 = (j + 3 < c) ? 1.f : 0.f;
        float v0 = Y2[(size_t)i0 * NH3 + lane];
        float v1 = Y2[(size_t)i1 * NH3 + lane];
        float v2 = Y2[(size_t)i2 * NH3 + lane];
        float v3 = Y2[(size_t)i3 * NH3 + lane];
        acc += v0;
        acc = fmaf(f1, v1, acc);
        acc = fmaf(f2, v2, acc);
        acc = fmaf(f3, v3, acc);
    }
    out[(size_t)n * NH3 + lane] = acc;
    float mx = acc;
    #pragma unroll
    for (int off = 32; off; off >>= 1) mx = fmaxf(mx, __shfl_xor(mx, off));
    float p = __expf(acc - mx);
    float s = p;
    #pragma unroll
    for (int off = 32; off; off >>= 1) s += __shfl_xor(s, off);
    out[(size_t)NN * NH3 + (size_t)n * NH3 + lane] = p / s;
}

// ---------------------------------------------------------------------------
__global__ __launch_bounds__(256, 2) void k_mega(MegaP P) {
    __shared__ __align__(16) char smem[16384];
    cg::grid_group grid = cg::this_grid();
    const int bid = blockIdx.x, tid = threadIdx.x;
    const int wid = tid >> 6, lane = tid & 63;

    // ---- phase 0: CSR + conversions + zero s1/s2 ----
    {
        int* lists = (int*)smem;            // 2 buffers x [4][64]
        int* cnts  = (int*)(smem + 2048);   // 2 buffers x [4]
        int par = 0;
        for (int vb = bid; vb < A_Z; vb += NBLK) {
            if (vb < A_CSR) {
                int* lds_list = lists + par * 256;
                int* lds_cnt  = cnts + par * 4;
                par ^= 1;
                const uint4* arow = (const uint4*)(P.adj + (size_t)vb * NN);
                uint4 v[4];
                #pragma unroll
                for (int it = 0; it < 4; ++it) v[it] = arow[wid * 256 + it * 64 + lane];
                const unsigned long long below = (1ull << lane) - 1ull;
                int base = 0;
                #pragma unroll
                for (int it = 0; it < 4; ++it) {
                    unsigned long long b0 = __ballot(v[it].x != 0u);
                    unsigned long long b1 = __ballot(v[it].y != 0u);
                    unsigned long long b2 = __ballot(v[it].z != 0u);
                    unsigned long long b3 = __ballot(v[it].w != 0u);
                    int pre = __popcll(b0 & below) + __popcll(b1 & below) +
                              __popcll(b2 & below) + __popcll(b3 & below);
                    int col0 = wid * 1024 + it * 256 + lane * 4;
                    int pos = base + pre;
                    if (v[it].x != 0u) { if (pos < 64) lds_list[wid * 64 + pos] = col0;     ++pos; }
                    if (v[it].y != 0u) { if (pos < 64) lds_list[wid * 64 + pos] = col0 + 1; ++pos; }
                    if (v[it].z != 0u) { if (pos < 64) lds_list[wid * 64 + pos] = col0 + 2; ++pos; }
                    if (v[it].w != 0u) { if (pos < 64) lds_list[wid * 64 + pos] = col0 + 3; ++pos; }
                    base += __popcll(b0) + __popcll(b1) + __popcll(b2) + __popcll(b3);
                }
                if (lane == 0) lds_cnt[wid] = base;
                __syncthreads();
                int c0 = lds_cnt[0], c1 = lds_cnt[1], c2 = lds_cnt[2], c3 = lds_cnt[3];
                int off = (wid > 0 ? c0 : 0) + (wid > 1 ? c1 : 0) + (wid > 2 ? c2 : 0);
                int my = lds_cnt[wid]; if (my > 64) my = 64;
                int* outp = P.nbr + vb * CAP;
                if (lane < my) {
                    int gpos = off + lane;
                    if (gpos < CAP) outp[gpos] = lds_list[wid * 64 + lane];
                }
                if (tid == 0) {
                    int tot = c0 + c1 + c2 + c3;
                    P.cnt[vb] = tot < CAP ? tot : CAP;
                }
            } else if (vb < A_X) {
                int i = ((vb - A_CSR) * 256 + tid) * 4;
                float4 v = *reinterpret_cast<const float4*>(P.x + i);
                ushort4 o;
                o.x = f2bf(v.x); o.y = f2bf(v.y); o.z = f2bf(v.z); o.w = f2bf(v.w);
                *reinterpret_cast<ushort4*>(P.xb + i) = o;
            } else if (vb < A_WATT) {
                int idx = (vb - A_X) * 256 + tid;
                int col = idx >> 9, f = idx & 511;
                int h = col >> 7, o = col & 127;
                P.Wattb[idx] = f2bf(P.W_att[h * (FIN * NH1) + f * NH1 + o]);
            } else if (vb < A_W1T) {
                int idx = (vb - A_WATT) * 256 + tid;
                int c = idx >> 9, r = idx & 511;
                P.W1t[idx] = f2bf(P.W1[(size_t)r * NH2 + c]);
            } else if (vb < A_W2B) {
                int i = ((vb - A_W1T) * 256 + tid) * 4;
                float4 v = *reinterpret_cast<const float4*>(P.W2 + i);
                ushort4 o;
                o.x = f2bf(v.x); o.y = f2bf(v.y); o.z = f2bf(v.z); o.w = f2bf(v.w);
                *reinterpret_cast<ushort4*>(P.W2b + i) = o;
            } else {
                int i = (vb - A_W2B) * 256 + tid;     // zero s1+s2 (32K floats)
                f32x4 z = {0.f, 0.f, 0.f, 0.f};
                *reinterpret_cast<f32x4*>(P.s1 + i * 4) = z;
            }
        }
    }
    grid.sync();

    // ---- phase 1: Whb = xb @ Wattb^T + scores (512 tiles, 1/block) ----
    gemm_tile(P.xb, P.Wattb, P.Whb, P.a, P.s1, P.s2, NH * NH1, FIN,
              bid & 7, bid >> 3, true, smem, tid);
    grid.sync();

    // ---- phase 2: attention (8 nodes/block, wave=head) ----
    for (int n = bid; n < NN; n += NBLK)
        attn_node(P.Whb, P.s1, P.s2, P.nbr, P.cnt, P.xrb, n, wid, lane);
    grid.sync();

    // ---- phase 3: y1b = xrb @ W1t^T (256 tiles) ----
    if (bid < 256)
        gemm_tile(P.xrb, P.W1t, P.y1b, nullptr, nullptr, nullptr, NH2, FIN,
                  bid & 3, bid >> 2, false, smem, tid);
    grid.sync();

    // ---- phase 4: g1 = relu(nbrsum(y1b)); y2 = g1 @ W2 ----
    for (int n = bid; n < NN; n += NBLK)
        g1y2_node(P.y1b, P.nbr, P.cnt, P.W2b, P.y2, n, tid, smem);
    grid.sync();

    // ---- phase 5: g2 = nbrsum(y2); out = [g2, softmax(g2)] ----
    #pragma unroll
    for (int i = 0; i < 2; ++i) {
        int n = bid + NBLK * (wid + 4 * i);
        final_node(P.y2, P.nbr, P.cnt, P.out, n, lane);
    }
}

// ---------------------------------------------------------------------------
extern "C" void kernel_launch(void* const* d_in, const int* in_sizes, int n_in,
                              void* d_out, int out_size, void* d_ws, size_t ws_size,
                              hipStream_t stream) {
    MegaP P;
    P.adj   = nullptr;
    P.x     = (const float*)d_in[0];
    P.adj   = (const float*)d_in[1];
    P.W_att = (const float*)d_in[2];
    P.a     = (const float*)d_in[3];
    P.W1    = (const float*)d_in[4];
    P.W2    = (const float*)d_in[5];
    P.out   = (float*)d_out;

    char* p = (char*)d_ws;
    P.xb    = (ushort*)p; p += (size_t)NN * FIN * 2;
    P.Wattb = (ushort*)p; p += (size_t)FIN * NH * NH1 * 2;
    P.W1t   = (ushort*)p; p += (size_t)NH2 * (NH * NH1) * 2;
    P.W2b   = (ushort*)p; p += (size_t)NH2 * NH3 * 2;
    P.Whb   = (ushort*)p; p += (size_t)NN * NH * NH1 * 2;
    P.s1    = (float*)p;  p += (size_t)NH * NN * 4;
    P.s2    = (float*)p;  p += (size_t)NH * NN * 4;
    P.nbr   = (int*)p;    p += (size_t)NN * CAP * 4;
    P.cnt   = (int*)p;    p += (size_t)NN * 4;
    P.xrb   = (ushort*)p; p += (size_t)NN * NH * NH1 * 2;
    P.y1b   = (ushort*)p; p += (size_t)NN * NH2 * 2;
    P.y2    = (float*)p;  p += (size_t)NN * NH3 * 4;

    void* args[] = { (void*)&P };
    hipLaunchCooperativeKernel((const void*)k_mega, dim3(NBLK), dim3(256),
                               args, 0, stream);
}

// Round 10
// 70.730 us; speedup vs baseline: 5.8459x; 5.8459x over previous
//
#include <hip/hip_runtime.h>
#include <hip/hip_bf16.h>

#define NN    4096
#define FIN   512
#define NH1   128
#define NH    4
#define NH2   256
#define NH3   64
#define CAP   64          // max neighbors per row (mean ~17)
#define ALPHA 0.2f

typedef float f32x4 __attribute__((ext_vector_type(4)));
typedef __bf16 bf16x8 __attribute__((ext_vector_type(8)));

__device__ __forceinline__ unsigned short f2bf(float f) {
    union { float f; unsigned u; } x; x.f = f;
    unsigned r = x.u + 0x7fff + ((x.u >> 16) & 1);   // RNE (finite inputs)
    return (unsigned short)(r >> 16);
}
__device__ __forceinline__ float bf2f(ushort u) {
    union { unsigned u; float f; } x; x.u = ((unsigned)u) << 16;
    return x.f;
}
__device__ __forceinline__ float bflo(unsigned w) {
    union { unsigned u; float f; } x; x.u = w << 16; return x.f;
}
__device__ __forceinline__ float bfhi(unsigned w) {
    union { unsigned u; float f; } x; x.u = w & 0xffff0000u; return x.f;
}

// ---------------------------------------------------------------------------
// k_conv: weight/input conversions + zero s1/s2 (CSR moved into k_attn_csr)
// ---------------------------------------------------------------------------
#define C_X     2048                // x -> bf16 (2M elems, 4/thread)
#define C_WATT  (C_X + 1024)        // W_att repack+cvt (256K elems)
#define C_W1T   (C_WATT + 512)      // W1 transpose+cvt (128K elems)
#define C_W2B   (C_W1T + 16)        // W2 flat cvt (16K elems, 4/thread)
#define C_Z     (C_W2B + 32)        // zero s1s2 (32K floats, float4/thread)

__global__ __launch_bounds__(256) void k_conv(
    const float* __restrict__ x, ushort* __restrict__ xb,
    const float* __restrict__ W_att, ushort* __restrict__ Wattb,
    const float* __restrict__ W1, ushort* __restrict__ W1t,
    const float* __restrict__ W2, ushort* __restrict__ W2b,
    float* __restrict__ s1s2) {
    int bid = blockIdx.x;
    int tid = threadIdx.x;
    if (bid < C_X) {
        int i = (bid * 256 + tid) * 4;                    // exact: 2M elems
        float4 v = *reinterpret_cast<const float4*>(x + i);
        ushort4 o;
        o.x = f2bf(v.x); o.y = f2bf(v.y); o.z = f2bf(v.z); o.w = f2bf(v.w);
        *reinterpret_cast<ushort4*>(xb + i) = o;
    } else if (bid < C_WATT) {
        int idx = (bid - C_X) * 256 + tid;                // col*512 + f
        int col = idx >> 9, f = idx & 511;
        int h = col >> 7, o = col & 127;
        Wattb[idx] = f2bf(W_att[h * (FIN * NH1) + f * NH1 + o]);
    } else if (bid < C_W1T) {
        int idx = (bid - C_WATT) * 256 + tid;             // c*512 + r, (256x512)
        int c = idx >> 9, r = idx & 511;
        W1t[idx] = f2bf(W1[(size_t)r * NH2 + c]);
    } else if (bid < C_W2B) {
        int i = ((bid - C_W1T) * 256 + tid) * 4;          // 16K elems flat
        float4 v = *reinterpret_cast<const float4*>(W2 + i);
        ushort4 o;
        o.x = f2bf(v.x); o.y = f2bf(v.y); o.z = f2bf(v.z); o.w = f2bf(v.w);
        *reinterpret_cast<ushort4*>(W2b + i) = o;
    } else {
        int i = (bid - C_W2B) * 256 + tid;                // 8192 float4 = 32K floats
        f32x4 z = {0.f, 0.f, 0.f, 0.f};
        *reinterpret_cast<f32x4*>(s1s2 + i * 4) = z;
    }
}

// ---------------------------------------------------------------------------
// bf16 MFMA GEMM, 2-phase pipelined dbuf (R8-verified). 64x64 tile, 4 waves.
// SCORES: fused s1/s2 accumulation from fp32 acc
// ---------------------------------------------------------------------------
#define GBM 64
#define GBN 64
#define GBK 64
template <int SCORES>
__global__ __launch_bounds__(256) void k_gemm_bf16(const ushort* __restrict__ A,
                                                   const ushort* __restrict__ Bt,
                                                   ushort* __restrict__ Cb,
                                                   const float* __restrict__ av,
                                                   float* __restrict__ s1,
                                                   float* __restrict__ s2,
                                                   int M, int N, int K) {
    __shared__ ushort As[2][GBM * GBK];
    __shared__ ushort Bs[2][GBN * GBK];
    const int tid = threadIdx.x;
    const int wid = tid >> 6;
    const int lane = tid & 63;
    const int row0 = blockIdx.y * GBM;
    const int col0 = blockIdx.x * GBN;
    const int wr = wid >> 1, wc = wid & 1;

    f32x4 acc[2][2] = {};
    const int nt = K / GBK;

    auto stage = [&](int buf, int k0) {
        #pragma unroll
        for (int j = 0; j < 2; ++j) {
            int ci = j * 256 + tid;
            int r = ci >> 3;
            int sc = (ci & 7) ^ (r & 7);
            const ushort* ga = A + (size_t)(row0 + r) * K + k0 + sc * 8;
            const ushort* gb = Bt + (size_t)(col0 + r) * K + k0 + sc * 8;
            ushort* la = &As[buf][(j * 256 + wid * 64) * 8];
            ushort* lb = &Bs[buf][(j * 256 + wid * 64) * 8];
            __builtin_amdgcn_global_load_lds(
                (const __attribute__((address_space(1))) unsigned int*)ga,
                (__attribute__((address_space(3))) unsigned int*)la, 16, 0, 0);
            __builtin_amdgcn_global_load_lds(
                (const __attribute__((address_space(1))) unsigned int*)gb,
                (__attribute__((address_space(3))) unsigned int*)lb, 16, 0, 0);
        }
    };

    stage(0, 0);
    __syncthreads();
    int cur = 0;
    for (int t = 0; t < nt; ++t) {
        if (t + 1 < nt) stage(cur ^ 1, (t + 1) * GBK);
        #pragma unroll
        for (int kk = 0; kk < 2; ++kk) {
            bf16x8 af[2], bfv[2];
            #pragma unroll
            for (int m = 0; m < 2; ++m) {
                int r = wr * 32 + m * 16 + (lane & 15);
                int kc = kk * 4 + (lane >> 4);
                int off = r * GBK + (((kc ^ (r & 7)) & 7) << 3);
                af[m] = *reinterpret_cast<const bf16x8*>(&As[cur][off]);
            }
            #pragma unroll
            for (int n = 0; n < 2; ++n) {
                int c = wc * 32 + n * 16 + (lane & 15);
                int kc = kk * 4 + (lane >> 4);
                int off = c * GBK + (((kc ^ (c & 7)) & 7) << 3);
                bfv[n] = *reinterpret_cast<const bf16x8*>(&Bs[cur][off]);
            }
            #pragma unroll
            for (int m = 0; m < 2; ++m)
                #pragma unroll
                for (int n = 0; n < 2; ++n)
                    acc[m][n] = __builtin_amdgcn_mfma_f32_16x16x32_bf16(af[m], bfv[n], acc[m][n], 0, 0, 0);
        }
        __syncthreads();
        cur ^= 1;
    }
    #pragma unroll
    for (int m = 0; m < 2; ++m)
        #pragma unroll
        for (int n = 0; n < 2; ++n) {
            int col = col0 + wc * 32 + n * 16 + (lane & 15);
            #pragma unroll
            for (int j2 = 0; j2 < 4; ++j2) {
                int row = row0 + wr * 32 + m * 16 + (lane >> 4) * 4 + j2;
                Cb[(size_t)row * N + col] = f2bf(acc[m][n][j2]);
            }
        }
    if (SCORES) {
        int h = col0 >> 7;
        float a1v[2], a2v[2];
        #pragma unroll
        for (int n = 0; n < 2; ++n) {
            int colh = (col0 & 127) + wc * 32 + n * 16 + (lane & 15);
            a1v[n] = av[h * 256 + colh];
            a2v[n] = av[h * 256 + 128 + colh];
        }
        #pragma unroll
        for (int m = 0; m < 2; ++m)
            #pragma unroll
            for (int j2 = 0; j2 < 4; ++j2) {
                float v1 = acc[m][0][j2] * a1v[0] + acc[m][1][j2] * a1v[1];
                float v2 = acc[m][0][j2] * a2v[0] + acc[m][1][j2] * a2v[1];
                #pragma unroll
                for (int off = 1; off < 16; off <<= 1) {
                    v1 += __shfl_xor(v1, off);
                    v2 += __shfl_xor(v2, off);
                }
                if ((lane & 15) == 0) {
                    int row = row0 + wr * 32 + m * 16 + (lane >> 4) * 4 + j2;
                    atomicAdd(&s1[h * NN + row], v1);
                    atomicAdd(&s2[h * NN + row], v2);
                }
            }
    }
}

// ---------------------------------------------------------------------------
// k_attn_csr: block per node. Builds neighbor list from adj row n (in LDS),
// writes nbr/cnt for downstream kernels, then softmax + aggregate -> xrb.
// adj read (64MB HBM) now overlaps the attention gather work.
// ---------------------------------------------------------------------------
__global__ __launch_bounds__(256) void k_attn_csr(const float* __restrict__ adj,
                                                  const ushort* __restrict__ Whb,
                                                  const float* __restrict__ s1,
                                                  const float* __restrict__ s2,
                                                  int* __restrict__ nbr,
                                                  int* __restrict__ cnt,
                                                  ushort* __restrict__ xrb) {
    __shared__ int lds_list[4][64];
    __shared__ int lds_cnt[4];
    __shared__ int mlist[CAP];
    __shared__ int stot;
    int n = blockIdx.x;
    int tid = threadIdx.x;
    int wid = tid >> 6;
    int lane = tid & 63;

    // ---- CSR for row n: wave wid scans cols [wid*1024, wid*1024+1024) ----
    const uint4* arow = (const uint4*)(adj + (size_t)n * NN);
    uint4 v[4];
    #pragma unroll
    for (int it = 0; it < 4; ++it) v[it] = arow[wid * 256 + it * 64 + lane];
    const unsigned long long below = (1ull << lane) - 1ull;
    int base = 0;
    #pragma unroll
    for (int it = 0; it < 4; ++it) {
        unsigned long long b0 = __ballot(v[it].x != 0u);
        unsigned long long b1 = __ballot(v[it].y != 0u);
        unsigned long long b2 = __ballot(v[it].z != 0u);
        unsigned long long b3 = __ballot(v[it].w != 0u);
        int pre = __popcll(b0 & below) + __popcll(b1 & below) +
                  __popcll(b2 & below) + __popcll(b3 & below);
        int col0 = wid * 1024 + it * 256 + lane * 4;
        int pos = base + pre;
        if (v[it].x != 0u) { if (pos < 64) lds_list[wid][pos] = col0;     ++pos; }
        if (v[it].y != 0u) { if (pos < 64) lds_list[wid][pos] = col0 + 1; ++pos; }
        if (v[it].z != 0u) { if (pos < 64) lds_list[wid][pos] = col0 + 2; ++pos; }
        if (v[it].w != 0u) { if (pos < 64) lds_list[wid][pos] = col0 + 3; ++pos; }
        base += __popcll(b0) + __popcll(b1) + __popcll(b2) + __popcll(b3);
    }
    if (lane == 0) lds_cnt[wid] = base;
    __syncthreads();
    int c0 = lds_cnt[0], c1 = lds_cnt[1], c2 = lds_cnt[2], c3 = lds_cnt[3];
    {
        int off = (wid > 0 ? c0 : 0) + (wid > 1 ? c1 : 0) + (wid > 2 ? c2 : 0);
        int my = lds_cnt[wid]; if (my > 64) my = 64;
        if (lane < my) {
            int gpos = off + lane;
            if (gpos < CAP) {
                mlist[gpos] = lds_list[wid][lane];
                nbr[n * CAP + gpos] = lds_list[wid][lane];
            }
        }
        if (tid == 0) {
            int tot = c0 + c1 + c2 + c3;
            stot = tot < CAP ? tot : CAP;
            cnt[n] = stot;
        }
    }
    __syncthreads();
    int c = stot;

    // ---- attention: wave wid = head h ----
    int h = wid;
    int m = mlist[lane < c ? lane : 0];
    float e = -1e30f;
    float s1n = s1[h * NN + n];
    if (lane < c) {
        float t = s1n + s2[h * NN + m];
        e = (t >= 0.0f) ? t : ALPHA * t;
    }
    float mx = e;
    #pragma unroll
    for (int off = 32; off; off >>= 1) mx = fmaxf(mx, __shfl_xor(mx, off));
    float p = (lane < c) ? __expf(e - mx) : 0.0f;
    float s = p;
    #pragma unroll
    for (int off = 32; off; off >>= 1) s += __shfl_xor(s, off);
    p /= s;
    const ushort* wb = Whb + h * 128 + 2 * lane;
    float acc0 = 0.0f, acc1 = 0.0f;
    int cp4 = (c + 3) & ~3;
    for (int j = 0; j < cp4; j += 4) {
        float p0 = __shfl(p, j),     p1 = __shfl(p, j + 1);
        float p2 = __shfl(p, j + 2), p3 = __shfl(p, j + 3);
        int   m0 = __shfl(m, j),     m1 = __shfl(m, j + 1);
        int   m2 = __shfl(m, j + 2), m3 = __shfl(m, j + 3);
        unsigned w0 = *reinterpret_cast<const unsigned*>(wb + (size_t)m0 * 512);
        unsigned w1 = *reinterpret_cast<const unsigned*>(wb + (size_t)m1 * 512);
        unsigned w2 = *reinterpret_cast<const unsigned*>(wb + (size_t)m2 * 512);
        unsigned w3 = *reinterpret_cast<const unsigned*>(wb + (size_t)m3 * 512);
        acc0 = fmaf(p0, bflo(w0), acc0); acc1 = fmaf(p0, bfhi(w0), acc1);
        acc0 = fmaf(p1, bflo(w1), acc0); acc1 = fmaf(p1, bfhi(w1), acc1);
        acc0 = fmaf(p2, bflo(w2), acc0); acc1 = fmaf(p2, bfhi(w2), acc1);
        acc0 = fmaf(p3, bflo(w3), acc0); acc1 = fmaf(p3, bfhi(w3), acc1);
    }
    unsigned ow = (unsigned)f2bf(fmaxf(acc0, 0.0f)) | ((unsigned)f2bf(fmaxf(acc1, 0.0f)) << 16);
    *reinterpret_cast<unsigned*>(xrb + (size_t)n * 512 + h * 128 + 2 * lane) = ow;
}

// ---------------------------------------------------------------------------
// Fused: g1 = relu(nbrsum(y1b)) in LDS, then y2[n] = g1 @ W2  (f32 out)
// ---------------------------------------------------------------------------
__global__ __launch_bounds__(256) void k_g1y2(const ushort* __restrict__ y1b,
                                              const int* __restrict__ nbr,
                                              const int* __restrict__ cnt,
                                              const ushort* __restrict__ W2b,
                                              float* __restrict__ y2) {
    __shared__ float g1s[NH2];
    __shared__ float part[4][NH3];
    int n = blockIdx.x;
    int tid = threadIdx.x;
    int c = cnt[n];
    const int* nb = nbr + n * CAP;
    if (tid < 128) {
        float acc0 = 0.0f, acc1 = 0.0f;
        const ushort* yb = y1b + 2 * tid;
        for (int j = 0; j < c; j += 4) {
            int i0 = nb[j];
            int i1 = nb[(j + 1 < c) ? j + 1 : j];
            int i2 = nb[(j + 2 < c) ? j + 2 : j];
            int i3 = nb[(j + 3 < c) ? j + 3 : j];
            float f1 = (j + 1 < c) ? 1.f : 0.f;
            float f2 = (j + 2 < c) ? 1.f : 0.f;
            float f3 = (j + 3 < c) ? 1.f : 0.f;
            unsigned w0 = *reinterpret_cast<const unsigned*>(yb + (size_t)i0 * NH2);
            unsigned w1 = *reinterpret_cast<const unsigned*>(yb + (size_t)i1 * NH2);
            unsigned w2 = *reinterpret_cast<const unsigned*>(yb + (size_t)i2 * NH2);
            unsigned w3 = *reinterpret_cast<const unsigned*>(yb + (size_t)i3 * NH2);
            acc0 += bflo(w0); acc1 += bfhi(w0);
            acc0 = fmaf(f1, bflo(w1), acc0); acc1 = fmaf(f1, bfhi(w1), acc1);
            acc0 = fmaf(f2, bflo(w2), acc0); acc1 = fmaf(f2, bfhi(w2), acc1);
            acc0 = fmaf(f3, bflo(w3), acc0); acc1 = fmaf(f3, bfhi(w3), acc1);
        }
        g1s[2 * tid]     = fmaxf(acc0, 0.0f);
        g1s[2 * tid + 1] = fmaxf(acc1, 0.0f);
    }
    __syncthreads();
    int q = tid >> 6, col = tid & 63;
    float acc = 0.0f;
    #pragma unroll 8
    for (int i = 0; i < 64; ++i) {
        int k = q * 64 + i;
        acc = fmaf(g1s[k], bf2f(W2b[k * NH3 + col]), acc);
    }
    part[q][col] = acc;
    __syncthreads();
    if (tid < 64)
        y2[(size_t)n * NH3 + tid] = part[0][tid] + part[1][tid] + part[2][tid] + part[3][tid];
}

// ---------------------------------------------------------------------------
// final: g2 = nbrsum(y2); write g2 and softmax(g2)
// ---------------------------------------------------------------------------
__global__ void k_final(const float* __restrict__ Y2, const int* __restrict__ nbr,
                        const int* __restrict__ cnt, float* __restrict__ out) {
    int n = blockIdx.x;
    int lane = threadIdx.x;            // 0..63
    int c = cnt[n];
    const int* nb = nbr + n * CAP;
    float acc = 0.0f;
    for (int j = 0; j < c; j += 4) {
        int i0 = nb[j];
        int i1 = nb[(j + 1 < c) ? j + 1 : j];
        int i2 = nb[(j + 2 < c) ? j + 2 : j];
        int i3 = nb[(j + 3 < c) ? j + 3 : j];
        float f1 = (j + 1 < c) ? 1.f : 0.f;
        float f2 = (j + 2 < c) ? 1.f : 0.f;
        float f3 = (j + 3 < c) ? 1.f : 0.f;
        float v0 = Y2[(size_t)i0 * NH3 + lane];
        float v1 = Y2[(size_t)i1 * NH3 + lane];
        float v2 = Y2[(size_t)i2 * NH3 + lane];
        float v3 = Y2[(size_t)i3 * NH3 + lane];
        acc += v0;
        acc = fmaf(f1, v1, acc);
        acc = fmaf(f2, v2, acc);
        acc = fmaf(f3, v3, acc);
    }
    out[(size_t)n * NH3 + lane] = acc;
    float mx = acc;
    #pragma unroll
    for (int off = 32; off; off >>= 1) mx = fmaxf(mx, __shfl_xor(mx, off));
    float p = __expf(acc - mx);
    float s = p;
    #pragma unroll
    for (int off = 32; off; off >>= 1) s += __shfl_xor(s, off);
    out[(size_t)NN * NH3 + (size_t)n * NH3 + lane] = p / s;
}

// ---------------------------------------------------------------------------
extern "C" void kernel_launch(void* const* d_in, const int* in_sizes, int n_in,
                              void* d_out, int out_size, void* d_ws, size_t ws_size,
                              hipStream_t stream) {
    const float* x     = (const float*)d_in[0];   // (4096, 512)
    const float* adj   = (const float*)d_in[1];   // (4096, 4096)
    const float* W_att = (const float*)d_in[2];   // (4, 512, 128)
    const float* a     = (const float*)d_in[3];   // (4, 256)
    const float* W1    = (const float*)d_in[4];   // (512, 256)
    const float* W2    = (const float*)d_in[5];   // (256, 64)
    float* out = (float*)d_out;

    char* p = (char*)d_ws;
    ushort* xb    = (ushort*)p; p += (size_t)NN * FIN * 2;           // 4 MB
    ushort* Wattb = (ushort*)p; p += (size_t)FIN * NH * NH1 * 2;     // 0.5 MB
    ushort* W1t   = (ushort*)p; p += (size_t)NH2 * (NH * NH1) * 2;   // 0.25 MB
    ushort* W2b   = (ushort*)p; p += (size_t)NH2 * NH3 * 2;          // 32 KB
    ushort* Whb   = (ushort*)p; p += (size_t)NN * NH * NH1 * 2;      // 4 MB
    float*  s1    = (float*)p;  p += (size_t)NH * NN * 4;
    float*  s2    = (float*)p;  p += (size_t)NH * NN * 4;
    int*    nbr   = (int*)p;    p += (size_t)NN * CAP * 4;           // 1 MB
    int*    cnt   = (int*)p;    p += (size_t)NN * 4;
    ushort* xrb   = (ushort*)p; p += (size_t)NN * NH * NH1 * 2;      // 4 MB
    ushort* y1b   = (ushort*)p; p += (size_t)NN * NH2 * 2;           // 2 MB
    float*  y2    = (float*)p;  p += (size_t)NN * NH3 * 4;           // 1 MB

    // A: conversions + zero s1/s2 (no CSR here anymore)
    k_conv<<<C_Z, 256, 0, stream>>>(x, xb, W_att, Wattb, W1, W1t, W2, W2b, s1);
    // B: Whb(bf16) = x @ Wcat + fused s1/s2 scores  (4096 x 512, K=512)
    k_gemm_bf16<1><<<dim3((NH * NH1) / GBN, NN / GBM), 256, 0, stream>>>(
        xb, Wattb, Whb, a, s1, s2, NN, NH * NH1, FIN);
    // C: CSR(row-local) + attention -> xrb ; writes nbr/cnt for D/E
    k_attn_csr<<<NN, 256, 0, stream>>>(adj, Whb, s1, s2, nbr, cnt, xrb);
    // D: y1b = xr @ W1  (4096 x 256, K=512)
    k_gemm_bf16<0><<<dim3(NH2 / GBN, NN / GBM), 256, 0, stream>>>(
        xrb, W1t, y1b, nullptr, nullptr, nullptr, NN, NH2, NH * NH1);
    // E: g1 = relu(nbrsum(y1b)); y2 = g1 @ W2
    k_g1y2<<<NN, 256, 0, stream>>>(y1b, nbr, cnt, W2b, y2);
    // F: g2 + softmax
    k_final<<<NN, 64, 0, stream>>>(y2, nbr, cnt, out);
}

// Round 11
// 67.505 us; speedup vs baseline: 6.1252x; 1.0478x over previous
//
#include <hip/hip_runtime.h>
#include <hip/hip_bf16.h>

#define NN    4096
#define FIN   512
#define NH1   128
#define NH    4
#define NH2   256
#define NH3   64
#define CAP   64          // max neighbors per row (mean ~17)
#define ALPHA 0.2f

typedef float f32x4 __attribute__((ext_vector_type(4)));
typedef __bf16 bf16x8 __attribute__((ext_vector_type(8)));

__device__ __forceinline__ unsigned short f2bf(float f) {
    union { float f; unsigned u; } x; x.f = f;
    unsigned r = x.u + 0x7fff + ((x.u >> 16) & 1);   // RNE (finite inputs)
    return (unsigned short)(r >> 16);
}
__device__ __forceinline__ float bf2f(ushort u) {
    union { unsigned u; float f; } x; x.u = ((unsigned)u) << 16;
    return x.f;
}
__device__ __forceinline__ float bflo(unsigned w) {
    union { unsigned u; float f; } x; x.u = w << 16; return x.f;
}
__device__ __forceinline__ float bfhi(unsigned w) {
    union { unsigned u; float f; } x; x.u = w & 0xffff0000u; return x.f;
}

// ---------------------------------------------------------------------------
// k_conv: weight/input conversions + zero s1/s2
// ---------------------------------------------------------------------------
#define C_X     2048                // x -> bf16 (2M elems, 4/thread)
#define C_WATT  (C_X + 1024)        // W_att repack+cvt (256K elems)
#define C_W1T   (C_WATT + 512)      // W1 transpose+cvt (128K elems)
#define C_W2B   (C_W1T + 16)        // W2 flat cvt (16K elems, 4/thread)
#define C_Z     (C_W2B + 32)        // zero s1s2 (32K floats, float4/thread)

__global__ __launch_bounds__(256) void k_conv(
    const float* __restrict__ x, ushort* __restrict__ xb,
    const float* __restrict__ W_att, ushort* __restrict__ Wattb,
    const float* __restrict__ W1, ushort* __restrict__ W1t,
    const float* __restrict__ W2, ushort* __restrict__ W2b,
    float* __restrict__ s1s2) {
    int bid = blockIdx.x;
    int tid = threadIdx.x;
    if (bid < C_X) {
        int i = (bid * 256 + tid) * 4;                    // exact: 2M elems
        float4 v = *reinterpret_cast<const float4*>(x + i);
        ushort4 o;
        o.x = f2bf(v.x); o.y = f2bf(v.y); o.z = f2bf(v.z); o.w = f2bf(v.w);
        *reinterpret_cast<ushort4*>(xb + i) = o;
    } else if (bid < C_WATT) {
        int idx = (bid - C_X) * 256 + tid;                // col*512 + f
        int col = idx >> 9, f = idx & 511;
        int h = col >> 7, o = col & 127;
        Wattb[idx] = f2bf(W_att[h * (FIN * NH1) + f * NH1 + o]);
    } else if (bid < C_W1T) {
        int idx = (bid - C_WATT) * 256 + tid;             // c*512 + r, (256x512)
        int c = idx >> 9, r = idx & 511;
        W1t[idx] = f2bf(W1[(size_t)r * NH2 + c]);
    } else if (bid < C_W2B) {
        int i = ((bid - C_W1T) * 256 + tid) * 4;          // 16K elems flat
        float4 v = *reinterpret_cast<const float4*>(W2 + i);
        ushort4 o;
        o.x = f2bf(v.x); o.y = f2bf(v.y); o.z = f2bf(v.z); o.w = f2bf(v.w);
        *reinterpret_cast<ushort4*>(W2b + i) = o;
    } else {
        int i = (bid - C_W2B) * 256 + tid;                // 8192 float4 = 32K floats
        f32x4 z = {0.f, 0.f, 0.f, 0.f};
        *reinterpret_cast<f32x4*>(s1s2 + i * 4) = z;
    }
}

// ---------------------------------------------------------------------------
// bf16 MFMA GEMM, templated tile height BM = 32*MT, BN=64, BK=64, 4 waves,
// double-buffered LDS (stage t+1 before compute t, one barrier per K-step).
// SCORES: fused s1/s2 accumulation from fp32 acc (requires N-tile == head cols)
// ---------------------------------------------------------------------------
template <int SCORES, int MT>
__global__ __launch_bounds__(256) void k_gemm(const ushort* __restrict__ A,
                                              const ushort* __restrict__ Bt,
                                              ushort* __restrict__ Cb,
                                              const float* __restrict__ av,
                                              float* __restrict__ s1,
                                              float* __restrict__ s2,
                                              int M, int N, int K) {
    __shared__ ushort As[2][32 * MT * 64];
    __shared__ ushort Bs[2][64 * 64];
    const int tid = threadIdx.x;
    const int wid = tid >> 6;
    const int lane = tid & 63;
    const int row0 = blockIdx.y * (32 * MT);
    const int col0 = blockIdx.x * 64;
    const int wr = wid >> 1, wc = wid & 1;

    f32x4 acc[MT][2] = {};
    const int nt = K / 64;

    auto stage = [&](int buf, int k0) {
        #pragma unroll
        for (int j = 0; j < MT; ++j) {          // A: MT*256 chunks
            int ci = j * 256 + tid;
            int r = ci >> 3;
            int sc = (ci & 7) ^ (r & 7);
            const ushort* ga = A + (size_t)(row0 + r) * K + k0 + sc * 8;
            ushort* la = &As[buf][(size_t)ci * 8];
            __builtin_amdgcn_global_load_lds(
                (const __attribute__((address_space(1))) unsigned int*)ga,
                (__attribute__((address_space(3))) unsigned int*)la, 16, 0, 0);
        }
        #pragma unroll
        for (int j = 0; j < 2; ++j) {           // B: 512 chunks
            int ci = j * 256 + tid;
            int r = ci >> 3;
            int sc = (ci & 7) ^ (r & 7);
            const ushort* gb = Bt + (size_t)(col0 + r) * K + k0 + sc * 8;
            ushort* lb = &Bs[buf][(size_t)ci * 8];
            __builtin_amdgcn_global_load_lds(
                (const __attribute__((address_space(1))) unsigned int*)gb,
                (__attribute__((address_space(3))) unsigned int*)lb, 16, 0, 0);
        }
    };

    stage(0, 0);
    __syncthreads();
    int cur = 0;
    for (int t = 0; t < nt; ++t) {
        if (t + 1 < nt) stage(cur ^ 1, (t + 1) * 64);
        #pragma unroll
        for (int kk = 0; kk < 2; ++kk) {
            bf16x8 af[MT], bfv[2];
            #pragma unroll
            for (int m = 0; m < MT; ++m) {
                int r = wr * (16 * MT) + m * 16 + (lane & 15);
                int kc = kk * 4 + (lane >> 4);
                int off = r * 64 + (((kc ^ (r & 7)) & 7) << 3);
                af[m] = *reinterpret_cast<const bf16x8*>(&As[cur][off]);
            }
            #pragma unroll
            for (int n = 0; n < 2; ++n) {
                int c = wc * 32 + n * 16 + (lane & 15);
                int kc = kk * 4 + (lane >> 4);
                int off = c * 64 + (((kc ^ (c & 7)) & 7) << 3);
                bfv[n] = *reinterpret_cast<const bf16x8*>(&Bs[cur][off]);
            }
            #pragma unroll
            for (int m = 0; m < MT; ++m)
                #pragma unroll
                for (int n = 0; n < 2; ++n)
                    acc[m][n] = __builtin_amdgcn_mfma_f32_16x16x32_bf16(af[m], bfv[n], acc[m][n], 0, 0, 0);
        }
        __syncthreads();
        cur ^= 1;
    }
    #pragma unroll
    for (int m = 0; m < MT; ++m)
        #pragma unroll
        for (int n = 0; n < 2; ++n) {
            int col = col0 + wc * 32 + n * 16 + (lane & 15);
            #pragma unroll
            for (int j2 = 0; j2 < 4; ++j2) {
                int row = row0 + wr * (16 * MT) + m * 16 + (lane >> 4) * 4 + j2;
                Cb[(size_t)row * N + col] = f2bf(acc[m][n][j2]);
            }
        }
    if (SCORES) {
        int h = col0 >> 7;
        float a1v[2], a2v[2];
        #pragma unroll
        for (int n = 0; n < 2; ++n) {
            int colh = (col0 & 127) + wc * 32 + n * 16 + (lane & 15);
            a1v[n] = av[h * 256 + colh];
            a2v[n] = av[h * 256 + 128 + colh];
        }
        #pragma unroll
        for (int m = 0; m < MT; ++m)
            #pragma unroll
            for (int j2 = 0; j2 < 4; ++j2) {
                float v1 = acc[m][0][j2] * a1v[0] + acc[m][1][j2] * a1v[1];
                float v2 = acc[m][0][j2] * a2v[0] + acc[m][1][j2] * a2v[1];
                #pragma unroll
                for (int off = 1; off < 16; off <<= 1) {
                    v1 += __shfl_xor(v1, off);
                    v2 += __shfl_xor(v2, off);
                }
                if ((lane & 15) == 0) {
                    int row = row0 + wr * (16 * MT) + m * 16 + (lane >> 4) * 4 + j2;
                    atomicAdd(&s1[h * NN + row], v1);
                    atomicAdd(&s2[h * NN + row], v2);
                }
            }
    }
}

// ---------------------------------------------------------------------------
// k_attn_csr: block per node. Builds neighbor list from adj row n (in LDS),
// writes nbr/cnt, then softmax + aggregate -> xrb. 8-way unrolled gather.
// ---------------------------------------------------------------------------
__global__ __launch_bounds__(256) void k_attn_csr(const float* __restrict__ adj,
                                                  const ushort* __restrict__ Whb,
                                                  const float* __restrict__ s1,
                                                  const float* __restrict__ s2,
                                                  int* __restrict__ nbr,
                                                  int* __restrict__ cnt,
                                                  ushort* __restrict__ xrb) {
    __shared__ int lds_list[4][64];
    __shared__ int lds_cnt[4];
    __shared__ int mlist[CAP];
    __shared__ int stot;
    int n = blockIdx.x;
    int tid = threadIdx.x;
    int wid = tid >> 6;
    int lane = tid & 63;

    const uint4* arow = (const uint4*)(adj + (size_t)n * NN);
    uint4 v[4];
    #pragma unroll
    for (int it = 0; it < 4; ++it) v[it] = arow[wid * 256 + it * 64 + lane];
    const unsigned long long below = (1ull << lane) - 1ull;
    int base = 0;
    #pragma unroll
    for (int it = 0; it < 4; ++it) {
        unsigned long long b0 = __ballot(v[it].x != 0u);
        unsigned long long b1 = __ballot(v[it].y != 0u);
        unsigned long long b2 = __ballot(v[it].z != 0u);
        unsigned long long b3 = __ballot(v[it].w != 0u);
        int pre = __popcll(b0 & below) + __popcll(b1 & below) +
                  __popcll(b2 & below) + __popcll(b3 & below);
        int col0 = wid * 1024 + it * 256 + lane * 4;
        int pos = base + pre;
        if (v[it].x != 0u) { if (pos < 64) lds_list[wid][pos] = col0;     ++pos; }
        if (v[it].y != 0u) { if (pos < 64) lds_list[wid][pos] = col0 + 1; ++pos; }
        if (v[it].z != 0u) { if (pos < 64) lds_list[wid][pos] = col0 + 2; ++pos; }
        if (v[it].w != 0u) { if (pos < 64) lds_list[wid][pos] = col0 + 3; ++pos; }
        base += __popcll(b0) + __popcll(b1) + __popcll(b2) + __popcll(b3);
    }
    if (lane == 0) lds_cnt[wid] = base;
    __syncthreads();
    int c0 = lds_cnt[0], c1 = lds_cnt[1], c2 = lds_cnt[2], c3 = lds_cnt[3];
    {
        int off = (wid > 0 ? c0 : 0) + (wid > 1 ? c1 : 0) + (wid > 2 ? c2 : 0);
        int my = lds_cnt[wid]; if (my > 64) my = 64;
        if (lane < my) {
            int gpos = off + lane;
            if (gpos < CAP) {
                mlist[gpos] = lds_list[wid][lane];
                nbr[n * CAP + gpos] = lds_list[wid][lane];
            }
        }
        if (tid == 0) {
            int tot = c0 + c1 + c2 + c3;
            stot = tot < CAP ? tot : CAP;
            cnt[n] = stot;
        }
    }
    __syncthreads();
    int c = stot;

    int h = wid;
    int m = mlist[lane < c ? lane : 0];
    float e = -1e30f;
    float s1n = s1[h * NN + n];
    if (lane < c) {
        float t = s1n + s2[h * NN + m];
        e = (t >= 0.0f) ? t : ALPHA * t;
    }
    float mx = e;
    #pragma unroll
    for (int off = 32; off; off >>= 1) mx = fmaxf(mx, __shfl_xor(mx, off));
    float p = (lane < c) ? __expf(e - mx) : 0.0f;
    float s = p;
    #pragma unroll
    for (int off = 32; off; off >>= 1) s += __shfl_xor(s, off);
    p /= s;
    // aggregate, 8 independent gathers in flight (p==0 masks j>=c lanes)
    const ushort* wb = Whb + h * 128 + 2 * lane;
    float acc0 = 0.0f, acc1 = 0.0f;
    int cp8 = (c + 7) & ~7;
    for (int j = 0; j < cp8; j += 8) {
        float pj[8]; int mj[8]; unsigned wj[8];
        #pragma unroll
        for (int u = 0; u < 8; ++u) {
            pj[u] = __shfl(p, j + u);
            mj[u] = __shfl(m, j + u);
        }
        #pragma unroll
        for (int u = 0; u < 8; ++u)
            wj[u] = *reinterpret_cast<const unsigned*>(wb + (size_t)mj[u] * 512);
        #pragma unroll
        for (int u = 0; u < 8; ++u) {
            acc0 = fmaf(pj[u], bflo(wj[u]), acc0);
            acc1 = fmaf(pj[u], bfhi(wj[u]), acc1);
        }
    }
    unsigned ow = (unsigned)f2bf(fmaxf(acc0, 0.0f)) | ((unsigned)f2bf(fmaxf(acc1, 0.0f)) << 16);
    *reinterpret_cast<unsigned*>(xrb + (size_t)n * 512 + h * 128 + 2 * lane) = ow;
}

// ---------------------------------------------------------------------------
// Fused: g1 = relu(nbrsum(y1b)) in LDS, then y2[n] = g1 @ W2  (f32 out)
// 8-way unrolled gather
// ---------------------------------------------------------------------------
__global__ __launch_bounds__(256) void k_g1y2(const ushort* __restrict__ y1b,
                                              const int* __restrict__ nbr,
                                              const int* __restrict__ cnt,
                                              const ushort* __restrict__ W2b,
                                              float* __restrict__ y2) {
    __shared__ float g1s[NH2];
    __shared__ float part[4][NH3];
    int n = blockIdx.x;
    int tid = threadIdx.x;
    int c = cnt[n];
    const int* nb = nbr + n * CAP;
    if (tid < 128) {
        float acc0 = 0.0f, acc1 = 0.0f;
        const ushort* yb = y1b + 2 * tid;
        for (int j = 0; j < c; j += 8) {
            int idx[8]; float f[8]; unsigned w[8];
            #pragma unroll
            for (int u = 0; u < 8; ++u) {
                idx[u] = nb[(j + u < c) ? j + u : j];
                f[u] = (j + u < c) ? 1.f : 0.f;
            }
            #pragma unroll
            for (int u = 0; u < 8; ++u)
                w[u] = *reinterpret_cast<const unsigned*>(yb + (size_t)idx[u] * NH2);
            #pragma unroll
            for (int u = 0; u < 8; ++u) {
                acc0 = fmaf(f[u], bflo(w[u]), acc0);
                acc1 = fmaf(f[u], bfhi(w[u]), acc1);
            }
        }
        g1s[2 * tid]     = fmaxf(acc0, 0.0f);
        g1s[2 * tid + 1] = fmaxf(acc1, 0.0f);
    }
    __syncthreads();
    int q = tid >> 6, col = tid & 63;
    float acc = 0.0f;
    #pragma unroll 8
    for (int i = 0; i < 64; ++i) {
        int k = q * 64 + i;
        acc = fmaf(g1s[k], bf2f(W2b[k * NH3 + col]), acc);
    }
    part[q][col] = acc;
    __syncthreads();
    if (tid < 64)
        y2[(size_t)n * NH3 + tid] = part[0][tid] + part[1][tid] + part[2][tid] + part[3][tid];
}

// ---------------------------------------------------------------------------
// final: 4 nodes/block (wave per node); g2 = nbrsum(y2); out = [g2, softmax]
// ---------------------------------------------------------------------------
__global__ __launch_bounds__(256) void k_final(const float* __restrict__ Y2,
                                               const int* __restrict__ nbr,
                                               const int* __restrict__ cnt,
                                               float* __restrict__ out) {
    int n = blockIdx.x * 4 + (threadIdx.x >> 6);
    int lane = threadIdx.x & 63;
    int c = cnt[n];
    const int* nb = nbr + n * CAP;
    float acc = 0.0f;
    for (int j = 0; j < c; j += 8) {
        int idx[8]; float f[8]; float v[8];
        #pragma unroll
        for (int u = 0; u < 8; ++u) {
            idx[u] = nb[(j + u < c) ? j + u : j];
            f[u] = (j + u < c) ? 1.f : 0.f;
        }
        #pragma unroll
        for (int u = 0; u < 8; ++u)
            v[u] = Y2[(size_t)idx[u] * NH3 + lane];
        #pragma unroll
        for (int u = 0; u < 8; ++u)
            acc = fmaf(f[u], v[u], acc);
    }
    out[(size_t)n * NH3 + lane] = acc;
    float mx = acc;
    #pragma unroll
    for (int off = 32; off; off >>= 1) mx = fmaxf(mx, __shfl_xor(mx, off));
    float p = __expf(acc - mx);
    float s = p;
    #pragma unroll
    for (int off = 32; off; off >>= 1) s += __shfl_xor(s, off);
    out[(size_t)NN * NH3 + (size_t)n * NH3 + lane] = p / s;
}

// ---------------------------------------------------------------------------
extern "C" void kernel_launch(void* const* d_in, const int* in_sizes, int n_in,
                              void* d_out, int out_size, void* d_ws, size_t ws_size,
                              hipStream_t stream) {
    const float* x     = (const float*)d_in[0];   // (4096, 512)
    const float* adj   = (const float*)d_in[1];   // (4096, 4096)
    const float* W_att = (const float*)d_in[2];   // (4, 512, 128)
    const float* a     = (const float*)d_in[3];   // (4, 256)
    const float* W1    = (const float*)d_in[4];   // (512, 256)
    const float* W2    = (const float*)d_in[5];   // (256, 64)
    float* out = (float*)d_out;

    char* p = (char*)d_ws;
    ushort* xb    = (ushort*)p; p += (size_t)NN * FIN * 2;           // 4 MB
    ushort* Wattb = (ushort*)p; p += (size_t)FIN * NH * NH1 * 2;     // 0.5 MB
    ushort* W1t   = (ushort*)p; p += (size_t)NH2 * (NH * NH1) * 2;   // 0.25 MB
    ushort* W2b   = (ushort*)p; p += (size_t)NH2 * NH3 * 2;          // 32 KB
    ushort* Whb   = (ushort*)p; p += (size_t)NN * NH * NH1 * 2;      // 4 MB
    float*  s1    = (float*)p;  p += (size_t)NH * NN * 4;
    float*  s2    = (float*)p;  p += (size_t)NH * NN * 4;
    int*    nbr   = (int*)p;    p += (size_t)NN * CAP * 4;           // 1 MB
    int*    cnt   = (int*)p;    p += (size_t)NN * 4;
    ushort* xrb   = (ushort*)p; p += (size_t)NN * NH * NH1 * 2;      // 4 MB
    ushort* y1b   = (ushort*)p; p += (size_t)NN * NH2 * 2;           // 2 MB
    float*  y2    = (float*)p;  p += (size_t)NN * NH3 * 4;           // 1 MB

    // A: conversions + zero s1/s2
    k_conv<<<C_Z, 256, 0, stream>>>(x, xb, W_att, Wattb, W1, W1t, W2, W2b, s1);
    // B: Whb(bf16) = x @ Wcat + fused s1/s2 scores (BM=64; 512 blocks)
    k_gemm<1, 2><<<dim3((NH * NH1) / 64, NN / 64), 256, 0, stream>>>(
        xb, Wattb, Whb, a, s1, s2, NN, NH * NH1, FIN);
    // C: CSR(row-local) + attention -> xrb ; writes nbr/cnt for D/E
    k_attn_csr<<<NN, 256, 0, stream>>>(adj, Whb, s1, s2, nbr, cnt, xrb);
    // D: y1b = xr @ W1  (BM=32; 512 blocks, 2/CU)
    k_gemm<0, 1><<<dim3(NH2 / 64, NN / 32), 256, 0, stream>>>(
        xrb, W1t, y1b, nullptr, nullptr, nullptr, NN, NH2, NH * NH1);
    // E: g1 = relu(nbrsum(y1b)); y2 = g1 @ W2
    k_g1y2<<<NN, 256, 0, stream>>>(y1b, nbr, cnt, W2b, y2);
    // F: g2 + softmax (4 nodes/block)
    k_final<<<NN / 4, 256, 0, stream>>>(y2, nbr, cnt, out);
}